// Round 8
// baseline (786.582 us; speedup 1.0000x reference)
//
#include <hip/hip_runtime.h>
#include <cstdint>
#include <cstddef>

#define B_    1024
#define L_    200
#define DIN_  256
#define DOUT_ 256
#define K_    8
#define M_    (B_ * L_)   // 204800

typedef __attribute__((ext_vector_type(8))) short bf16x8;
typedef __attribute__((ext_vector_type(4))) float f32x4;

__device__ __forceinline__ float bf2f(unsigned short u) {
  union { unsigned int i; float f; } w; w.i = ((unsigned int)u) << 16; return w.f;
}
__device__ __forceinline__ unsigned short f2bf(float f) {
  union { float f; unsigned int i; } w; w.f = f;
  unsigned int x = w.i;
  return (unsigned short)((x + 0x7fffu + ((x >> 16) & 1u)) >> 16);
}

// async global->LDS 16B: LDS dest = uniform base + lane*16 (HW-applied)
__device__ __forceinline__ void gload_lds16(const unsigned short* g, unsigned short* l) {
  __builtin_amdgcn_global_load_lds(
      (const __attribute__((address_space(1))) void*)g,
      (__attribute__((address_space(3))) void*)l, 16, 0, 0);
}

// ---------------- kernel 0: split W into bf16 hi/mid/lo, fragment order + logits init
__global__ __launch_bounds__(256)
void wt_prep(const float* __restrict__ W, const float* __restrict__ rlog,
             unsigned short* __restrict__ Wall, float* __restrict__ logitsW)
{
  const int k = blockIdx.x;    // 256
  const int n = threadIdx.x;   // 256
  const int gi = blockIdx.x * 256 + threadIdx.x;
  if (gi < K_ * L_) logitsW[gi] = rlog[gi];

  float x = W[k * DOUT_ + n];
  unsigned short h = f2bf(x);
  float r = x - bf2f(h);
  unsigned short m = f2bf(r);
  float r2 = r - bf2f(m);
  unsigned short l = f2bf(r2);
  const int k0b = k >> 5, quad = (k >> 3) & 3, j = k & 7;
  const int ntg = n >> 4, lr = n & 15;
  const int lane = quad * 16 + lr;
  Wall[(((size_t)k0b * 3 + 0) * 16 + ntg) * 512 + lane * 8 + j] = h;
  Wall[(((size_t)k0b * 3 + 1) * 16 + ntg) * 512 + lane * 8 + j] = m;
  Wall[(((size_t)k0b * 3 + 2) * 16 + ntg) * 512 + lane * 8 + j] = l;
}

// ---------------- kernel 1: UNCHANGED from R7 (196 us, MfmaUtil 34%)
__global__ __launch_bounds__(256, 3)
void gemm_mapped(const float* __restrict__ A,
                 const unsigned short* __restrict__ Wall,
                 float* __restrict__ C)
{
  const int t    = threadIdx.x;
  const int wave = t >> 6;
  const int lane = t & 63;
  const int quad = lane >> 4;
  const int lr   = lane & 15;
  const int m0   = blockIdx.x * 128 + wave * 32;
  const int nt0  = blockIdx.y * 8;

  __shared__ unsigned short Bs[2][24 * 512];

  f32x4 acc[2][8];
  #pragma unroll
  for (int mt = 0; mt < 2; ++mt)
    #pragma unroll
    for (int nt = 0; nt < 8; ++nt)
      acc[mt][nt] = (f32x4){0.f, 0.f, 0.f, 0.f};

  bf16x8 ah[2], am[2], al[2];
  float4 Af[2][2];

#define STAGE(K0B, BUF) do { \
    _Pragma("unroll") \
    for (int _i = 0; _i < 6; ++_i) { \
      const int _c   = wave * 6 + _i; \
      const int _s   = _c >> 3; \
      const int _ntl = _c & 7; \
      const unsigned short* _g = Wall + \
          ((((size_t)(K0B) * 3 + _s) * 16 + nt0 + _ntl) * 512) + lane * 8; \
      gload_lds16(_g, &Bs[BUF][_c * 512]); \
    } \
  } while (0)

  const float* ap0 = A + (size_t)(m0 + lr) * DIN_ + quad * 8;
  const float* ap1 = A + (size_t)(m0 + 16 + lr) * DIN_ + quad * 8;

  STAGE(0, 0);
  Af[0][0] = *(const float4*)(ap0);
  Af[0][1] = *(const float4*)(ap0 + 4);
  Af[1][0] = *(const float4*)(ap1);
  Af[1][1] = *(const float4*)(ap1 + 4);
  __syncthreads();

  for (int k0b = 0; k0b < 8; ++k0b) {
    const int cur = k0b & 1;
    if (k0b < 7) STAGE(k0b + 1, cur ^ 1);

    #pragma unroll
    for (int mt = 0; mt < 2; ++mt) {
      float xs[8] = {Af[mt][0].x, Af[mt][0].y, Af[mt][0].z, Af[mt][0].w,
                     Af[mt][1].x, Af[mt][1].y, Af[mt][1].z, Af[mt][1].w};
      #pragma unroll
      for (int j = 0; j < 8; ++j) {
        unsigned short h = f2bf(xs[j]);
        float r = xs[j] - bf2f(h);
        unsigned short mm = f2bf(r);
        float r2 = r - bf2f(mm);
        unsigned short ll = f2bf(r2);
        ah[mt][j] = (short)h; am[mt][j] = (short)mm; al[mt][j] = (short)ll;
      }
    }
    if (k0b < 7) {
      const int ko = (k0b + 1) * 32;
      Af[0][0] = *(const float4*)(ap0 + ko);
      Af[0][1] = *(const float4*)(ap0 + ko + 4);
      Af[1][0] = *(const float4*)(ap1 + ko);
      Af[1][1] = *(const float4*)(ap1 + ko + 4);
    }

#define GROUP(NT) do { \
    bf16x8 bh = *(const bf16x8*)&Bs[cur][(0 * 8 + (NT)) * 512 + lane * 8]; \
    bf16x8 bm = *(const bf16x8*)&Bs[cur][(1 * 8 + (NT)) * 512 + lane * 8]; \
    bf16x8 bl = *(const bf16x8*)&Bs[cur][(2 * 8 + (NT)) * 512 + lane * 8]; \
    f32x4 c0 = acc[0][NT], c1 = acc[1][NT]; \
    c0 = __builtin_amdgcn_mfma_f32_16x16x32_bf16(ah[0], bh, c0, 0, 0, 0); \
    c1 = __builtin_amdgcn_mfma_f32_16x16x32_bf16(ah[1], bh, c1, 0, 0, 0); \
    c0 = __builtin_amdgcn_mfma_f32_16x16x32_bf16(ah[0], bm, c0, 0, 0, 0); \
    c1 = __builtin_amdgcn_mfma_f32_16x16x32_bf16(ah[1], bm, c1, 0, 0, 0); \
    c0 = __builtin_amdgcn_mfma_f32_16x16x32_bf16(am[0], bh, c0, 0, 0, 0); \
    c1 = __builtin_amdgcn_mfma_f32_16x16x32_bf16(am[1], bh, c1, 0, 0, 0); \
    c0 = __builtin_amdgcn_mfma_f32_16x16x32_bf16(ah[0], bl, c0, 0, 0, 0); \
    c1 = __builtin_amdgcn_mfma_f32_16x16x32_bf16(ah[1], bl, c1, 0, 0, 0); \
    c0 = __builtin_amdgcn_mfma_f32_16x16x32_bf16(am[0], bm, c0, 0, 0, 0); \
    c1 = __builtin_amdgcn_mfma_f32_16x16x32_bf16(am[1], bm, c1, 0, 0, 0); \
    c0 = __builtin_amdgcn_mfma_f32_16x16x32_bf16(al[0], bh, c0, 0, 0, 0); \
    c1 = __builtin_amdgcn_mfma_f32_16x16x32_bf16(al[1], bh, c1, 0, 0, 0); \
    acc[0][NT] = c0; acc[1][NT] = c1; \
  } while (0)

    GROUP(0); GROUP(1); GROUP(2); GROUP(3);
    GROUP(4); GROUP(5); GROUP(6); GROUP(7);
#undef GROUP

    __syncthreads();
  }
#undef STAGE

  #pragma unroll
  for (int mt = 0; mt < 2; ++mt)
    #pragma unroll
    for (int nt = 0; nt < 8; ++nt)
      #pragma unroll
      for (int r = 0; r < 4; ++r) {
        int row = m0 + mt * 16 + quad * 4 + r;
        C[(size_t)row * DOUT_ + (nt0 + nt) * 16 + lr] = acc[mt][nt][r];
      }
}

// ---------------- kernel 2: fused routing iteration, one block per b.
// Phase A: masked softmax (wave w -> capsules 2w,2w+1). Phase B: Z partials per wave
// (l-interleave), LDS combine + squash. FINAL: write caps to d_out and exit.
// Else Phase C: delta[k][l] = caps_k . mapped_l over all l (caps in LDS, mapped L2-hot),
// 6-step butterfly over lanes, per-b partials -> d_out scratch (deterministic).
template <bool FINAL>
__global__ __launch_bounds__(256)
void route_kernel(const float* __restrict__ mapped, const float* __restrict__ logits,
                  const int* __restrict__ seq_len, float* __restrict__ out)
{
  const int b    = blockIdx.x;
  const int t    = threadIdx.x;
  const int lane = t & 63;
  const int wave = t >> 6;
  const int len  = seq_len[b];          // 1..200
  __shared__ float w[K_][204];          // 6528 B
  __shared__ float red[4][K_][DOUT_];   // 32 KB; red[0] re-used as caps_s, red[1] as delta_s

  // ---- phase A: softmax
  #pragma unroll
  for (int kk = 0; kk < 2; ++kk) {
    const int k = wave * 2 + kk;
    float v[4];
    float mx = -3.4028235e38f;
    #pragma unroll
    for (int i = 0; i < 4; ++i) {
      int l = lane + 64 * i;
      v[i] = (l < len) ? logits[k * L_ + l] : -3.4028235e38f;
      mx = fmaxf(mx, v[i]);
    }
    #pragma unroll
    for (int s = 1; s < 64; s <<= 1) mx = fmaxf(mx, __shfl_xor(mx, s, 64));
    float e[4]; float sum = 0.f;
    #pragma unroll
    for (int i = 0; i < 4; ++i) {
      int l = lane + 64 * i;
      e[i] = (l < len) ? __expf(v[i] - mx) : 0.f;
      sum += e[i];
    }
    #pragma unroll
    for (int s = 1; s < 64; s <<= 1) sum += __shfl_xor(sum, s, 64);
    float inv = 1.f / sum;
    #pragma unroll
    for (int i = 0; i < 4; ++i) {
      int l = lane + 64 * i;
      if (l < 204) w[k][l] = e[i] * inv;   // exactly 0 for l >= len
    }
  }
  __syncthreads();

  // ---- phase B: Z partials (wave handles l = wave*4 + 16i)
  f32x4 acc[K_];
  #pragma unroll
  for (int k = 0; k < K_; ++k) acc[k] = (f32x4){0.f, 0.f, 0.f, 0.f};
  const float* mp = mapped + (size_t)b * L_ * DOUT_ + lane * 4;
  const int lceil = (len + 3) & ~3;
  for (int l = wave * 4; l < lceil; l += 16) {
    float4 m0 = *(const float4*)(mp + (size_t)(l + 0) * DOUT_);
    float4 m1 = *(const float4*)(mp + (size_t)(l + 1) * DOUT_);
    float4 m2 = *(const float4*)(mp + (size_t)(l + 2) * DOUT_);
    float4 m3 = *(const float4*)(mp + (size_t)(l + 3) * DOUT_);
    #pragma unroll
    for (int k = 0; k < K_; ++k) {
      float4 wv = *(const float4*)&w[k][l];
      f32x4 c = acc[k];
      c.x += wv.x * m0.x + wv.y * m1.x + wv.z * m2.x + wv.w * m3.x;
      c.y += wv.x * m0.y + wv.y * m1.y + wv.z * m2.y + wv.w * m3.y;
      c.z += wv.x * m0.z + wv.y * m1.z + wv.z * m2.z + wv.w * m3.z;
      c.w += wv.x * m0.w + wv.y * m1.w + wv.z * m2.w + wv.w * m3.w;
      acc[k] = c;
    }
  }
  #pragma unroll
  for (int k = 0; k < K_; ++k)
    *(f32x4*)&red[wave][k][lane * 4] = acc[k];
  __syncthreads();

  // ---- phase B2: combine + squash (wave handles capsules 2w, 2w+1)
  #pragma unroll
  for (int kk = 0; kk < 2; ++kk) {
    const int k = wave * 2 + kk;
    float4 s0 = *(const float4*)&red[0][k][lane * 4];
    float4 s1 = *(const float4*)&red[1][k][lane * 4];
    float4 s2 = *(const float4*)&red[2][k][lane * 4];
    float4 s3 = *(const float4*)&red[3][k][lane * 4];
    float4 z;
    z.x = (s0.x + s1.x) + (s2.x + s3.x);
    z.y = (s0.y + s1.y) + (s2.y + s3.y);
    z.z = (s0.z + s1.z) + (s2.z + s3.z);
    z.w = (s0.w + s1.w) + (s2.w + s3.w);
    float sq = z.x * z.x + z.y * z.y + z.z * z.z + z.w * z.w;
    #pragma unroll
    for (int s = 1; s < 64; s <<= 1) sq += __shfl_xor(sq, s, 64);
    float scale = sq / ((1.f + sq) * sqrtf(sq + 1e-8f));
    float4 o;
    o.x = scale * z.x; o.y = scale * z.y; o.z = scale * z.z; o.w = scale * z.w;
    if (FINAL) {
      *(float4*)&out[((size_t)b * K_ + k) * DOUT_ + lane * 4] = o;  // caps
    } else {
      *(float4*)&red[0][k][lane * 4] = o;   // caps_s (same lane read it above)
    }
  }
  if (FINAL) return;
  __syncthreads();

  // ---- phase C: delta (all l in [0,200))
  float* caps_s  = &red[0][0][0];   // [K][256]
  float* delta_s = &red[1][0][0];   // 1600 floats (fits in red[1]'s 2048)
  float4 cv[K_];
  #pragma unroll
  for (int k = 0; k < K_; ++k) cv[k] = *(const float4*)&caps_s[k * DOUT_ + lane * 4];

  for (int l0 = wave * 4; l0 < L_; l0 += 16) {
    float4 m0 = *(const float4*)(mp + (size_t)(l0 + 0) * DOUT_);
    float4 m1 = *(const float4*)(mp + (size_t)(l0 + 1) * DOUT_);
    float4 m2 = *(const float4*)(mp + (size_t)(l0 + 2) * DOUT_);
    float4 m3 = *(const float4*)(mp + (size_t)(l0 + 3) * DOUT_);
    #pragma unroll
    for (int k = 0; k < K_; ++k) {
      float p0 = cv[k].x * m0.x + cv[k].y * m0.y + cv[k].z * m0.z + cv[k].w * m0.w;
      float p1 = cv[k].x * m1.x + cv[k].y * m1.y + cv[k].z * m1.z + cv[k].w * m1.w;
      float p2 = cv[k].x * m2.x + cv[k].y * m2.y + cv[k].z * m2.z + cv[k].w * m2.w;
      float p3 = cv[k].x * m3.x + cv[k].y * m3.y + cv[k].z * m3.z + cv[k].w * m3.w;
      #pragma unroll
      for (int s = 1; s < 64; s <<= 1) {
        p0 += __shfl_xor(p0, s, 64);
        p1 += __shfl_xor(p1, s, 64);
        p2 += __shfl_xor(p2, s, 64);
        p3 += __shfl_xor(p3, s, 64);
      }
      // lanes k*4+dl (k<8 -> lanes 0..31) hold the writers
      if (lane == k * 4 + 0) delta_s[k * L_ + l0 + 0] = p0;
      if (lane == k * 4 + 1) delta_s[k * L_ + l0 + 1] = p1;
      if (lane == k * 4 + 2) delta_s[k * L_ + l0 + 2] = p2;
      if (lane == k * 4 + 3) delta_s[k * L_ + l0 + 3] = p3;
    }
  }
  __syncthreads();
  // per-b partials -> out (d_out scratch): [b][1600], coalesced
  for (int i = t; i < K_ * L_; i += 256)
    out[(size_t)b * (K_ * L_) + i] = delta_s[i];
}

// ---------------- kernel 3: logits += sum_b partials[b][k][l]  (deterministic order)
__global__ __launch_bounds__(256)
void reduce_kernel(const float* __restrict__ partials, float* __restrict__ logits)
{
  int i = blockIdx.x * 256 + threadIdx.x;
  if (i < K_ * L_) {
    float s = 0.f;
    #pragma unroll 8
    for (int b = 0; b < B_; ++b) s += partials[(size_t)b * (K_ * L_) + i];
    logits[i] += s;
  }
}

extern "C" void kernel_launch(void* const* d_in, const int* in_sizes, int n_in,
                              void* d_out, int out_size, void* d_ws, size_t ws_size,
                              hipStream_t stream)
{
  const float* behav = (const float*)d_in[0];
  const int*   slen  = (const int*)d_in[1];
  const float* rlog  = (const float*)d_in[2];
  const float* W     = (const float*)d_in[3];
  float* outp = (float*)d_out;   // iters 0/1: per-b delta partials (6.55 MB of 8 MB); final: caps

  char* ws = (char*)d_ws;
  float* logitsW  = (float*)ws;                           // 6400 B
  unsigned short* Wall = (unsigned short*)(ws + 458752);  // 384 KiB (ends 851968)
  float* mapped   = (float*)(ws + (1 << 20));             // 200 MiB fp32 (proven layout)

  wt_prep<<<dim3(256), 256, 0, stream>>>(W, rlog, Wall, logitsW);
  gemm_mapped<<<dim3(1600, 2), 256, 0, stream>>>(behav, Wall, mapped);
  for (int it = 0; it < 2; ++it) {
    route_kernel<false><<<dim3(B_), 256, 0, stream>>>(mapped, logitsW, slen, outp);
    reduce_kernel<<<dim3(7), 256, 0, stream>>>(outp, logitsW);
  }
  route_kernel<true><<<dim3(B_), 256, 0, stream>>>(mapped, logitsW, slen, outp);
}